// Round 1
// 159.259 us; speedup vs baseline: 1.0614x; 1.0614x over previous
//
#include <hip/hip_runtime.h>
#include <hip/hip_bf16.h>
#include <math.h>

#define D_DIM 2048
#define L_DIM 64
#define E_NUM 64
#define H_DIM 64

typedef float f32x4_t __attribute__((ext_vector_type(4)));
typedef __bf16 bf16x8_t __attribute__((ext_vector_type(8)));

// ---------------- workspace layout (bytes) ----------------
// WS_UPART: 128*2048 f32 partial sums of u      (1 MB)
// WS_U:     2048 f32 u = x^T wout               (8 KB)
// WS_V:     64 f32 v = Wg_in u
// WS_META:  sel[2] (int) + g[2] (float)
// WS_WB:    128*2048 bf16 selected expert weights (512 KB)
#define WS_UPART 0u
#define WS_U     (128u * 2048u * 4u)
#define WS_V     (WS_U + 2048u * 4u)
#define WS_META  (WS_V + 256u)
#define WS_WB    (WS_META + 64u)

// ---------------- kernel 1: u_part[c][d] = sum_{s in chunk c} x[s,d]*wout[s] ----
__global__ void k_upart(const float* __restrict__ x, const float* __restrict__ wout,
                        float* __restrict__ upart) {
  const int d4 = (blockIdx.x * 256 + threadIdx.x) * 4;  // gridDim.x == 2
  const int s0 = blockIdx.y * 64;                        // gridDim.y == 128
  const float* xp = x + (size_t)s0 * D_DIM + d4;
  float4 acc = make_float4(0.f, 0.f, 0.f, 0.f);
#pragma unroll 8
  for (int i = 0; i < 64; ++i) {
    const float w = wout[s0 + i];
    const float4 xv = *reinterpret_cast<const float4*>(xp + (size_t)i * D_DIM);
    acc.x += xv.x * w; acc.y += xv.y * w; acc.z += xv.z * w; acc.w += xv.w * w;
  }
  *reinterpret_cast<float4*>(upart + (size_t)blockIdx.y * D_DIM + d4) = acc;
}

// ---------------- kernel 1b: u[d] = sum_c u_part[c][d] ----------------
__global__ void k_ufinish(const float* __restrict__ upart, float* __restrict__ u) {
  const int d = blockIdx.x * 256 + threadIdx.x;  // grid 8 x 256
  float s = 0.f;
#pragma unroll 8
  for (int c = 0; c < 128; ++c) s += upart[(size_t)c * D_DIM + d];
  u[d] = s;
}

// ---------------- kernel 2a: v[h] = Wg_in[h,:] . u ----------------
__global__ void k_v(const float* __restrict__ wg_in, const float* __restrict__ u,
                    float* __restrict__ v) {
  const int h = blockIdx.x;  // 64 blocks
  const int t = threadIdx.x; // 256 threads
  const float4* wr = reinterpret_cast<const float4*>(wg_in + (size_t)h * D_DIM);
  const float4* ur = reinterpret_cast<const float4*>(u);
  float s = 0.f;
#pragma unroll
  for (int i = t; i < 512; i += 256) {
    const float4 a = wr[i];
    const float4 b = ur[i];
    s += a.x * b.x + a.y * b.y + a.z * b.z + a.w * b.w;
  }
  __shared__ float red[4];
#pragma unroll
  for (int off = 32; off; off >>= 1) s += __shfl_down(s, off, 64);
  if ((t & 63) == 0) red[t >> 6] = s;
  __syncthreads();
  if (t == 0) v[h] = red[0] + red[1] + red[2] + red[3];
}

// ---------------- kernel 2b: scores, top-2, softmax ----------------
__global__ void k_gate(const float* __restrict__ wg_lin, const float* __restrict__ v,
                       int* __restrict__ sel, float* __restrict__ g) {
  __shared__ float vv[H_DIM];
  __shared__ float sc[E_NUM];
  const int t = threadIdx.x;  // 64 threads
  vv[t] = v[t];
  __syncthreads();
  float s = 0.f;
#pragma unroll 8
  for (int hh = 0; hh < H_DIM; ++hh) s += wg_lin[t * H_DIM + hh] * vv[hh];
  sc[t] = s;
  __syncthreads();
  if (t == 0) {
    int b1 = 0; float m1 = sc[0];
    for (int e = 1; e < E_NUM; ++e) { if (sc[e] > m1) { m1 = sc[e]; b1 = e; } }
    int b2 = -1; float m2 = -3.4e38f;
    for (int e = 0; e < E_NUM; ++e) {
      if (e != b1 && sc[e] > m2) { m2 = sc[e]; b2 = e; }
    }
    const float e2 = expf(m2 - m1);
    const float g0 = 1.0f / (1.0f + e2);
    sel[0] = b1; sel[1] = b2;
    g[0] = g0; g[1] = 1.0f - g0;
  }
}

// ---------------- kernel 2c: cast selected experts to bf16 ----------------
__global__ void k_wb(const float* __restrict__ we, const int* __restrict__ sel,
                     __hip_bfloat16* __restrict__ wb) {
  const int n = blockIdx.x;         // 128 rows = 2 experts x 64
  const int e = sel[n >> 6];
  const int l = n & 63;
  const float* src = we + ((size_t)e * L_DIM + l) * D_DIM;
  const int t = threadIdx.x;        // 256 threads, 8 elems each
  const float4 a = reinterpret_cast<const float4*>(src)[2 * t];
  const float4 b = reinterpret_cast<const float4*>(src)[2 * t + 1];
  union { __hip_bfloat16 h[8]; uint4 u; } pk;
  pk.h[0] = __float2bfloat16(a.x); pk.h[1] = __float2bfloat16(a.y);
  pk.h[2] = __float2bfloat16(a.z); pk.h[3] = __float2bfloat16(a.w);
  pk.h[4] = __float2bfloat16(b.x); pk.h[5] = __float2bfloat16(b.y);
  pk.h[6] = __float2bfloat16(b.z); pk.h[7] = __float2bfloat16(b.w);
  reinterpret_cast<uint4*>(wb + (size_t)n * D_DIM)[t] = pk.u;
}

// ---------------- kernel 3: bf16 MFMA GEMM + normalize + gelu + combine ------
// Split-K x4 version: 1024 threads = 16 waves. Wave group kg = tid>>8 owns
// K-range [kg*512, kg*512+512) in 8 steps of BK=64; within a group the 4
// waves each own 32 of the 128 output cols (identical layout to previous
// 256-thread version). 4 private LDS staging regions (20992 B each = 84 KB
// total -> 1 block/CU but 16 waves/CU = 4 waves/SIMD instead of 1).
// After K-loop: 4 partial 32x128 acc tiles summed in LDS, then the same
// normalize+gelu+combine epilogue (run by tid<256).
__device__ __forceinline__ void async_ld16(const void* gp, void* lp) {
  __builtin_amdgcn_global_load_lds(
      (const __attribute__((address_space(1))) unsigned int*)gp,
      (__attribute__((address_space(3))) unsigned int*)lp, 16, 0, 0);
}

__device__ __forceinline__ float gelu_f(float v) {
  return 0.5f * v * (1.0f + erff(v * 0.70710678118654752440f));
}

#define STG_BYTES 20992  // per-kgroup staging: A 32*144 + B 128*64*2

__global__ __launch_bounds__(1024) void k_moe_gemm(
    const float* __restrict__ x, const __hip_bfloat16* __restrict__ wb,
    const float* __restrict__ gw, float* __restrict__ out) {
  __shared__ __align__(16) unsigned char lds[4 * STG_BYTES];  // 83968 B

  const int tid = threadIdx.x;
  const int kg = tid >> 8;         // K-group 0..3
  const int lt = tid & 255;        // group-local thread
  const int wc = (tid >> 6) & 3;   // wave col within group (owns cols wc*32..+32)
  const int lane = tid & 63;
  const int m0 = blockIdx.x * 32;
  const float g0 = gw[0], g1 = gw[1];

  unsigned char* ldsA0 = lds + kg * STG_BYTES;
  unsigned char* ldsB0 = ldsA0 + 32 * 144;

  // A staging: group-local thread t -> row lt>>3, 8 f32 at col (lt&7)*8 within BK
  const int ar = lt >> 3, ac = lt & 7;
  const float* gA = x + (size_t)(m0 + ar) * D_DIM + kg * 512 + ac * 8;
  unsigned char* ldsAw = ldsA0 + ar * 144 + ac * 16;

  const int fr = lane & 15, fq = lane >> 4;

  f32x4_t acc00 = {0.f, 0.f, 0.f, 0.f};
  f32x4_t acc01 = acc00, acc10 = acc00, acc11 = acc00;

  for (int kk = 0; kk < 8; ++kk) {
    const int k0 = kg * 512 + kk * 64;
    if (kk) __syncthreads();
    // ---- stage A: f32 global -> bf16 -> LDS ----
    const float4 a0 = *reinterpret_cast<const float4*>(gA + kk * 64);
    const float4 a1 = *reinterpret_cast<const float4*>(gA + kk * 64 + 4);
    union { __hip_bfloat16 h[8]; uint4 u; } pk;
    pk.h[0] = __float2bfloat16(a0.x); pk.h[1] = __float2bfloat16(a0.y);
    pk.h[2] = __float2bfloat16(a0.z); pk.h[3] = __float2bfloat16(a0.w);
    pk.h[4] = __float2bfloat16(a1.x); pk.h[5] = __float2bfloat16(a1.y);
    pk.h[6] = __float2bfloat16(a1.z); pk.h[7] = __float2bfloat16(a1.w);
    *reinterpret_cast<uint4*>(ldsAw) = pk.u;
    // ---- stage B: async global->LDS, XOR swizzle of 16B k-chunks ----
#pragma unroll
    for (int i = 0; i < 4; ++i) {
      const int c = i * 256 + lt;           // chunk 0..1023
      const int r = c >> 3, p = c & 7;
      const int kc = p ^ (r & 7);
      async_ld16(wb + (size_t)r * D_DIM + k0 + kc * 8, ldsB0 + c * 16);
    }
    __syncthreads();
    // ---- fragments ----
    union fragu { uint4 u; bf16x8_t v; };
    fragu af[2][2], bfr[2][2];
#pragma unroll
    for (int mt = 0; mt < 2; ++mt)
#pragma unroll
      for (int ks = 0; ks < 2; ++ks)
        af[mt][ks].u = *reinterpret_cast<const uint4*>(
            ldsA0 + (mt * 16 + fr) * 144 + ks * 64 + fq * 16);
#pragma unroll
    for (int nt = 0; nt < 2; ++nt)
#pragma unroll
      for (int ks = 0; ks < 2; ++ks) {
        const int r = wc * 32 + nt * 16 + fr;
        const int kq = ks * 4 + fq;
        bfr[nt][ks].u = *reinterpret_cast<const uint4*>(
            ldsB0 + r * 128 + ((kq ^ (r & 7)) * 16));
      }
    acc00 = __builtin_amdgcn_mfma_f32_16x16x32_bf16(af[0][0].v, bfr[0][0].v, acc00, 0, 0, 0);
    acc00 = __builtin_amdgcn_mfma_f32_16x16x32_bf16(af[0][1].v, bfr[0][1].v, acc00, 0, 0, 0);
    acc01 = __builtin_amdgcn_mfma_f32_16x16x32_bf16(af[0][0].v, bfr[1][0].v, acc01, 0, 0, 0);
    acc01 = __builtin_amdgcn_mfma_f32_16x16x32_bf16(af[0][1].v, bfr[1][1].v, acc01, 0, 0, 0);
    acc10 = __builtin_amdgcn_mfma_f32_16x16x32_bf16(af[1][0].v, bfr[0][0].v, acc10, 0, 0, 0);
    acc10 = __builtin_amdgcn_mfma_f32_16x16x32_bf16(af[1][1].v, bfr[0][1].v, acc10, 0, 0, 0);
    acc11 = __builtin_amdgcn_mfma_f32_16x16x32_bf16(af[1][0].v, bfr[1][0].v, acc11, 0, 0, 0);
    acc11 = __builtin_amdgcn_mfma_f32_16x16x32_bf16(af[1][1].v, bfr[1][1].v, acc11, 0, 0, 0);
  }
  __syncthreads();
  // ---- partial z tiles: zbuf[kg][32][132] f32 overlay staging LDS ----
  {
    float* z = reinterpret_cast<float*>(lds) + kg * (32 * 132);
    const int colbase = wc * 32 + fr;
#pragma unroll
    for (int reg = 0; reg < 4; ++reg) {
      const int r0 = fq * 4 + reg;
      z[r0 * 132 + colbase]             = acc00[reg];
      z[r0 * 132 + colbase + 16]        = acc01[reg];
      z[(16 + r0) * 132 + colbase]      = acc10[reg];
      z[(16 + r0) * 132 + colbase + 16] = acc11[reg];
    }
  }
  __syncthreads();
  // ---- sum 4 K-group partials into group 0's buffer ----
  {
    float* zb = reinterpret_cast<float*>(lds);
    const int r = tid >> 5;              // 0..31
    const int cb = (tid & 31) * 4;       // 0..124
    const int o = r * 132 + cb;
    f32x4_t s = *reinterpret_cast<f32x4_t*>(zb + o)
              + *reinterpret_cast<f32x4_t*>(zb + 1 * 4224 + o)
              + *reinterpret_cast<f32x4_t*>(zb + 2 * 4224 + o)
              + *reinterpret_cast<f32x4_t*>(zb + 3 * 4224 + o);
    *reinterpret_cast<f32x4_t*>(zb + o) = s;
  }
  __syncthreads();
  float* z = reinterpret_cast<float*>(lds);
  float* ps = reinterpret_cast<float*>(lds + 4 * 16896);  // [32][8] partial sumsq
  if (tid < 256) {
    const int r = tid >> 3, seg = tid & 7;
    float s = 0.f;
#pragma unroll
    for (int i2 = 0; i2 < 16; ++i2) {
      const float t2 = z[r * 132 + seg * 16 + i2];
      s += t2 * t2;
    }
    ps[r * 8 + seg] = s;
  }
  __syncthreads();
  if (tid < 256) {
    const int r = tid >> 3, j = tid & 7;
    const float s0 = ps[r * 8 + 0] + ps[r * 8 + 1] + ps[r * 8 + 2] + ps[r * 8 + 3];
    const float s1 = ps[r * 8 + 4] + ps[r * 8 + 5] + ps[r * 8 + 6] + ps[r * 8 + 7];
    const float i0 = 1.0f / fmaxf(sqrtf(s0), 1e-12f);
    const float i1 = 1.0f / fmaxf(sqrtf(s1), 1e-12f);
    float o[8];
#pragma unroll
    for (int i2 = 0; i2 < 8; ++i2) {
      const int c = j * 8 + i2;
      const float za = z[r * 132 + c] * i0;
      const float zb = z[r * 132 + 64 + c] * i1;
      o[i2] = g0 * gelu_f(za) + g1 * gelu_f(zb);
    }
    float4* op = reinterpret_cast<float4*>(out + (size_t)(m0 + r) * 64 + j * 8);
    op[0] = make_float4(o[0], o[1], o[2], o[3]);
    op[1] = make_float4(o[4], o[5], o[6], o[7]);
  }
}

// ---------------- launch ----------------
extern "C" void kernel_launch(void* const* d_in, const int* in_sizes, int n_in,
                              void* d_out, int out_size, void* d_ws, size_t ws_size,
                              hipStream_t stream) {
  (void)in_sizes; (void)n_in; (void)out_size; (void)ws_size;
  const float* x      = (const float*)d_in[0];
  const float* wg_in  = (const float*)d_in[1];
  const float* wg_lin = (const float*)d_in[2];
  const float* wg_out = (const float*)d_in[3];
  const float* we     = (const float*)d_in[4];
  float* out = (float*)d_out;
  char* ws = (char*)d_ws;

  float* upart = (float*)(ws + WS_UPART);
  float* u     = (float*)(ws + WS_U);
  float* v     = (float*)(ws + WS_V);
  int*   sel   = (int*)(ws + WS_META);
  float* g     = (float*)(ws + WS_META + 8);
  __hip_bfloat16* wb = (__hip_bfloat16*)(ws + WS_WB);

  k_upart  <<<dim3(2, 128), 256, 0, stream>>>(x, wg_out, upart);
  k_ufinish<<<8, 256, 0, stream>>>(upart, u);
  k_v      <<<64, 256, 0, stream>>>(wg_in, u, v);
  k_gate   <<<1, 64, 0, stream>>>(wg_lin, v, sel, g);
  k_wb     <<<128, 256, 0, stream>>>(we, sel, wb);
  k_moe_gemm<<<256, 1024, 0, stream>>>(x, wb, g, out);
}